// Round 4
// baseline (824.848 us; speedup 1.0000x reference)
//
#include <hip/hip_runtime.h>

#define Tn      8192
#define Cn      1024
#define En      8
#define Fn      2752
#define MAXROWS 18432
#define NT1     32      // Cn/32 K-tiles for gemm1
#define NT2     86      // Fn/32 K-tiles for gemm2

typedef __bf16 bf16;
typedef bf16  bf16x8 __attribute__((ext_vector_type(8)));
typedef bf16  bf16x4 __attribute__((ext_vector_type(4)));
typedef float f32x4  __attribute__((ext_vector_type(4)));

__device__ __forceinline__ void gload16(const bf16* g, bf16* l) {
  __builtin_amdgcn_global_load_lds(
      (const __attribute__((address_space(1))) unsigned int*)g,
      (__attribute__((address_space(3))) unsigned int*)l, 16, 0, 0);
}

#define BARRIER() __builtin_amdgcn_s_barrier()
#define VMCNT(N)  asm volatile("s_waitcnt vmcnt(" #N ")" ::: "memory")
#define MFMA(d, va, vb) d = __builtin_amdgcn_mfma_f32_16x16x32_bf16(va, vb, d, 0, 0, 0)

// bijective XCD-chunk swizzle: consecutive remapped ids land on the same XCD.
__device__ __forceinline__ int xcd_swz(int flat, int nwg) {
  int xcd = flat & 7, loc = flat >> 3;
  int q = nwg >> 3, r = nwg & 7;
  return (xcd < r ? xcd * (q + 1) : r * (q + 1) + (xcd - r) * q) + loc;
}

// ---------------- gating ------------------------------------------------------
__global__ __launch_bounds__(256) void gate_kernel(
    const float* __restrict__ x, const float* __restrict__ wgate,
    int* __restrict__ topk_i, float* __restrict__ topk_w, int* __restrict__ counts)
{
  int lane = threadIdx.x & 63;
  int wid  = threadIdx.x >> 6;
  int t = blockIdx.x * 4 + wid;
  const float* xr = x + (size_t)t * Cn;
  float acc[En];
#pragma unroll
  for (int e = 0; e < En; ++e) acc[e] = 0.f;
  for (int c = lane; c < Cn; c += 64) {
    float xv = xr[c];
#pragma unroll
    for (int e = 0; e < En; ++e) acc[e] = fmaf(xv, wgate[e * Cn + c], acc[e]);
  }
#pragma unroll
  for (int e = 0; e < En; ++e) {
#pragma unroll
    for (int o = 32; o > 0; o >>= 1) acc[e] += __shfl_xor(acc[e], o, 64);
  }
  if (lane == 0) {
    float mx = acc[0];
#pragma unroll
    for (int e = 1; e < En; ++e) mx = fmaxf(mx, acc[e]);
    float p[En], Z = 0.f;
#pragma unroll
    for (int e = 0; e < En; ++e) { p[e] = __expf(acc[e] - mx); Z += p[e]; }
    int i0 = 0;
#pragma unroll
    for (int e = 1; e < En; ++e) if (p[e] > p[i0]) i0 = e;
    int i1 = (i0 == 0) ? 1 : 0;
#pragma unroll
    for (int e = 0; e < En; ++e) if (e != i0 && p[e] > p[i1]) i1 = e;
    float s0 = p[i0] / Z, s1 = p[i1] / Z;
    float inv = 1.f / (s0 + s1 + 1e-9f);
    topk_i[2 * t] = i0;       topk_i[2 * t + 1] = i1;
    topk_w[2 * t] = s0 * inv; topk_w[2 * t + 1] = s1 * inv;
    atomicAdd(&counts[i0], 1);
    atomicAdd(&counts[i1], 1);
  }
}

__global__ void offsets_kernel(const int* __restrict__ counts,
                               int* __restrict__ fill, int* __restrict__ off)
{
  if (threadIdx.x == 0 && blockIdx.x == 0) {
    int o = 0;
    for (int e = 0; e < En; ++e) {
      off[e]  = o;
      fill[e] = o;
      o += (counts[e] + 255) & ~255;   // 256-row expert padding
    }
    off[En] = o;
  }
}

__global__ __launch_bounds__(256) void scatter_kernel(
    const int* __restrict__ topk_i, const float* __restrict__ topk_w,
    int* __restrict__ fill, int* __restrict__ tok_list, float* __restrict__ wgt_list,
    int* __restrict__ inv_rows)
{
  int t = blockIdx.x * 256 + threadIdx.x;
#pragma unroll
  for (int j = 0; j < 2; ++j) {
    int e = topk_i[2 * t + j];
    int pos = atomicAdd(&fill[e], 1);
    tok_list[pos] = t;
    wgt_list[pos] = topk_w[2 * t + j];
    inv_rows[2 * t + j] = pos;
  }
}

__global__ __launch_bounds__(256) void gather_x(
    const float* __restrict__ x, const int* __restrict__ tok_list, bf16* __restrict__ xg)
{
  int row = blockIdx.x;
  int tok = tok_list[row];
  int c = threadIdx.x * 4;
  float4 v = make_float4(0.f, 0.f, 0.f, 0.f);
  if (tok >= 0) v = *(const float4*)(x + (size_t)tok * Cn + c);
  bf16x4 pv;
  pv[0] = (bf16)v.x; pv[1] = (bf16)v.y; pv[2] = (bf16)v.z; pv[3] = (bf16)v.w;
  *(bf16x4*)(xg + (size_t)row * Cn + c) = pv;
}

// ---------------- fast transpose + fp32->bf16 ---------------------------------
__global__ __launch_bounds__(256) void transpose_cvt(
    const float* __restrict__ src, bf16* __restrict__ dst, int M, int N)
{
  __shared__ float L[64][65];
  src += (size_t)blockIdx.z * M * N;
  dst += (size_t)blockIdx.z * M * N;
  const int bm = blockIdx.x * 64;
  const int bn = blockIdx.y * 64;
  const int tid = threadIdx.x;
  const int mr = tid >> 4, nseg = tid & 15;
#pragma unroll
  for (int p = 0; p < 4; ++p) {
    int m = p * 16 + mr;
    float4 v = *(const float4*)(src + (size_t)(bm + m) * N + bn + nseg * 4);
    L[nseg * 4 + 0][m] = v.x;
    L[nseg * 4 + 1][m] = v.y;
    L[nseg * 4 + 2][m] = v.z;
    L[nseg * 4 + 3][m] = v.w;
  }
  __syncthreads();
  const int nr = tid >> 3, mseg = tid & 7;
#pragma unroll
  for (int q = 0; q < 2; ++q) {
    int n = q * 32 + nr;
    bf16x8 w;
#pragma unroll
    for (int j = 0; j < 8; ++j) w[j] = (bf16)L[n][mseg * 8 + j];
    *(bf16x8*)(dst + (size_t)(bn + n) * M + bm + mseg * 8) = w;
  }
}

// LDS K-tile layout (BK=32, 64B rows = 4 x 16B slots):
//   LDS[row][slot] = G[row][slot ^ ((row>>1)&3)]   -> conflict-free b128 frag reads
// staging lane: row = tid>>2, gseg = (tid&3) ^ ((tid>>3)&3)
// frag read:   slot = q ^ ((fr>>1)&3),  q = lane>>4, fr = lane&15

// ---------------- GEMM1: h = wgt * silu(xg@wgT') * (xg@wuT') ------------------
// PERSISTENT: 512 thr / 8 waves (wave = 128m x 32F x {g,u}), block 256m x 128F.
// BK=32, dbuf 64KB, 2 phases/K-tile (16-MFMA bursts), vmcnt(4)/vmcnt(1) ledger.
// Each block loops m-tiles (stride gridDim.y); next tile-0 stages issue BEFORE
// the previous m-tile's epilogue (silu+store hides the cold-tile latency).
__global__ __launch_bounds__(512, 2) void gemm1_kernel(
    const bf16* __restrict__ xg, const bf16* __restrict__ wgT, const bf16* __restrict__ wuT,
    const int* __restrict__ off, const int* __restrict__ counts,
    const float* __restrict__ wgt_list, bf16* __restrict__ h, int row_lo, int mt)
{
  const int gdx = gridDim.x;                 // 22
  const int nwg = gdx * gridDim.y;
  const int sw  = xcd_swz(blockIdx.y * gdx + blockIdx.x, nwg);
  const int bx  = sw % gdx;
  const int by0 = sw / gdx;
  const int mstride = gridDim.y;

  const int n0F = bx * 128;

  // per-buffer (elements): A0 @0, A1 @4096, Bg @8192, Bu @12288  (32KB/buf)
  __shared__ bf16 sm[2][16384];              // 64 KB

  const int tid = threadIdx.x;
  const int lane = tid & 63, wid = tid >> 6;
  const int wm   = (wid >> 2) * 128;         // wave m-half
  const int wnvF = (wid & 3) * 32;           // wave F-col window (32 cols)
  const int fr = lane & 15, q = lane >> 4;
  const int lrow = tid >> 2;                 // staging row 0..127
  const int gseg = (tid & 3) ^ ((tid >> 3) & 3);
  const int tt = (q ^ ((fr >> 1) & 3)) * 8;
  const int rq = (lane >> 4) * 4, cl = lane & 15;

  int brow = n0F + lrow; if (brow > Fn - 1) brow = Fn - 1;   // ragged F tail clamp

  f32x4 accg[8][2], accu[8][2];
  int prev_m0 = -1, prev_base = 0, prev_cnt = 0;

#define EPI1() do {                                                            \
    _Pragma("unroll")                                                          \
    for (int mi = 0; mi < 8; ++mi) {                                           \
      _Pragma("unroll")                                                        \
      for (int r = 0; r < 4; ++r) {                                            \
        int grow = prev_m0 + wm + mi * 16 + rq + r;                            \
        float w = (grow - prev_base < prev_cnt) ? wgt_list[grow] : 0.f;        \
        bf16* hr = h + (size_t)(grow - row_lo) * Fn + n0F;                     \
        _Pragma("unroll")                                                      \
        for (int nj = 0; nj < 2; ++nj) {                                       \
          int fc = wnvF + nj * 16;                                             \
          if (n0F + fc < Fn) {                                                 \
            float g = accg[mi][nj][r], u = accu[mi][nj][r];                    \
            hr[fc + cl] = (bf16)(w * u * (g / (1.f + __expf(-g))));            \
          }                                                                    \
        }                                                                      \
      }                                                                        \
    }                                                                          \
  } while (0)

  for (int ms = by0; ms < mt; ms += mstride) {
    const int m0 = row_lo + ms * 256;
    if (m0 >= off[En]) break;
    int e = 0;
    while (off[e + 1] <= m0) ++e;
    const int base = off[e], cnt = counts[e];

    const bf16* a0p = xg + (size_t)(m0 + lrow) * Cn + gseg * 8;
    const bf16* a1p = a0p + (size_t)128 * Cn;
    const bf16* bgp = wgT + (size_t)e * Fn * Cn + (size_t)brow * Cn + gseg * 8;
    const bf16* bup = wuT + (size_t)e * Fn * Cn + (size_t)brow * Cn + gseg * 8;

    // stage tile 0 into buf 0 (issue order: A0, A1, Bg, Bu)
    {
      bf16* Nx = &sm[0][0];
      gload16(a0p, Nx + tid * 8);
      gload16(a1p, Nx + 4096 + tid * 8);
      gload16(bgp, Nx + 8192 + tid * 8);
      gload16(bup, Nx + 12288 + tid * 8);
    }

    // deferred epilogue of previous m-tile hides tile-0 latency
    if (prev_m0 >= 0) EPI1();

#pragma unroll
    for (int mi = 0; mi < 8; ++mi)
#pragma unroll
      for (int nj = 0; nj < 2; ++nj) { accg[mi][nj] = (f32x4)(0.f); accu[mi][nj] = (f32x4)(0.f); }

    VMCNT(1);           // A0,A1,Bg landed; Bu may be in flight
    BARRIER();

    for (int kt = 0; kt < NT1; ++kt) {
      const bf16* S = &sm[kt & 1][0];
      bf16* Nx = &sm[(kt + 1) & 1][0];
      const bool lastt = (kt == NT1 - 1);
      const int ko = (kt + 1) * 32;

      bf16x8 a[8], bg[2], bu[2];
      // ---- P0: read a + bg ; stage next tile (A0,A1,Bg,Bu) ; MFMA gate
#pragma unroll
      for (int mi = 0; mi < 8; ++mi)
        a[mi] = *(const bf16x8*)(S + (wm + mi * 16 + fr) * 32 + tt);
#pragma unroll
      for (int nj = 0; nj < 2; ++nj)
        bg[nj] = *(const bf16x8*)(S + 8192 + (wnvF + nj * 16 + fr) * 32 + tt);
      if (!lastt) {
        gload16(a0p + ko, Nx + tid * 8);
        gload16(a1p + ko, Nx + 4096 + tid * 8);
        gload16(bgp + ko, Nx + 8192 + tid * 8);
        gload16(bup + ko, Nx + 12288 + tid * 8);
      }
      __builtin_amdgcn_s_setprio(1);
#pragma unroll
      for (int mi = 0; mi < 8; ++mi)
#pragma unroll
        for (int nj = 0; nj < 2; ++nj)
          MFMA(accg[mi][nj], a[mi], bg[nj]);
      __builtin_amdgcn_s_setprio(0);
      if (lastt) { VMCNT(0); } else { VMCNT(4); }   // Bu(kt) landed
      BARRIER();

      // ---- P1: read bu ; MFMA up
#pragma unroll
      for (int nj = 0; nj < 2; ++nj)
        bu[nj] = *(const bf16x8*)(S + 12288 + (wnvF + nj * 16 + fr) * 32 + tt);
      __builtin_amdgcn_s_setprio(1);
#pragma unroll
      for (int mi = 0; mi < 8; ++mi)
#pragma unroll
        for (int nj = 0; nj < 2; ++nj)
          MFMA(accu[mi][nj], a[mi], bu[nj]);
      __builtin_amdgcn_s_setprio(0);
      if (!lastt) { VMCNT(1); }   // A0',A1',Bg' landed for next P0; Bu' in flight
      BARRIER();
    }

    prev_m0 = m0; prev_base = base; prev_cnt = cnt;
  }

  if (prev_m0 >= 0) EPI1();
#undef EPI1
}

// ---------------- GEMM2: h2[row] = h[row] @ wdT' ------------------------------
// 512 thr / 8 waves, block 256m x 256n, wave 128m x 64n (n-frags interleaved:
// col = ni*64 + wnq*16 so P0 reads confine to B-chunk 0). BK=32, dbuf 64KB,
// 2 phases/K-tile, vmcnt(4)/vmcnt(1). grid (pre-swizzle): x = n (4), y = m.
__global__ __launch_bounds__(512, 2) void gemm2_kernel(
    const bf16* __restrict__ h, const bf16* __restrict__ wdT,
    const int* __restrict__ off, bf16* __restrict__ h2, int row_lo)
{
  const int gdx = gridDim.x;   // 4
  const int nwg = gdx * gridDim.y;
  const int sw = xcd_swz(blockIdx.y * gdx + blockIdx.x, nwg);
  const int bx = sw % gdx, by = sw / gdx;

  const int m0 = row_lo + by * 256;
  if (m0 >= off[En]) return;
  int e = 0;
  while (off[e + 1] <= m0) ++e;
  const int n0 = bx * 256;

  // per-buffer (elements): A0 @0, A1 @4096, B0 @8192, B1 @12288  (32KB/buf)
  __shared__ bf16 sm[2][16384];              // 64 KB

  const int tid = threadIdx.x;
  const int lane = tid & 63, wid = tid >> 6;
  const int wm  = (wid >> 2) * 128;          // wave m-half
  const int wnq = (wid & 3) * 16;            // wave n-offset within each 64-col group
  const int fr = lane & 15, q = lane >> 4;
  const int lrow = tid >> 2;                 // staging row 0..127
  const int gseg = (tid & 3) ^ ((tid >> 3) & 3);
  const int tt = (q ^ ((fr >> 1) & 3)) * 8;

  const bf16* a0p = h   + (size_t)(m0 - row_lo + lrow) * Fn + gseg * 8;
  const bf16* a1p = a0p + (size_t)128 * Fn;
  const bf16* b0p = wdT + (size_t)e * Cn * Fn + (size_t)(n0 + lrow) * Fn + gseg * 8;
  const bf16* b1p = b0p + (size_t)128 * Fn;

  f32x4 acc[8][4];
#pragma unroll
  for (int mi = 0; mi < 8; ++mi)
#pragma unroll
    for (int ni = 0; ni < 4; ++ni) acc[mi][ni] = (f32x4)(0.f);

  // prologue: stage tile 0 (issue order: A0, A1, B0, B1)
  {
    bf16* Nx = &sm[0][0];
    gload16(a0p, Nx + tid * 8);
    gload16(a1p, Nx + 4096 + tid * 8);
    gload16(b0p, Nx + 8192 + tid * 8);
    gload16(b1p, Nx + 12288 + tid * 8);
  }
  VMCNT(1);            // A0,A1,B0 landed; B1 may be in flight
  BARRIER();

  for (int kt = 0; kt < NT2; ++kt) {
    const bf16* S = &sm[kt & 1][0];
    bf16* Nx = &sm[(kt + 1) & 1][0];
    const bool lastt = (kt == NT2 - 1);
    const int ko = (kt + 1) * 32;

    bf16x8 a[8], bl[2], bh[2];
    // ---- P0: read a + b-low (chunk B0 only, all waves) ; stage next ; MFMA low
#pragma unroll
    for (int mi = 0; mi < 8; ++mi)
      a[mi] = *(const bf16x8*)(S + (wm + mi * 16 + fr) * 32 + tt);
#pragma unroll
    for (int j = 0; j < 2; ++j)
      bl[j] = *(const bf16x8*)(S + 8192 + (j * 64 + wnq + fr) * 32 + tt);
    if (!lastt) {
      gload16(a0p + ko, Nx + tid * 8);
      gload16(a1p + ko, Nx + 4096 + tid * 8);
      gload16(b0p + ko, Nx + 8192 + tid * 8);
      gload16(b1p + ko, Nx + 12288 + tid * 8);
    }
    __builtin_amdgcn_s_setprio(1);
#pragma unroll
    for (int mi = 0; mi < 8; ++mi)
#pragma unroll
      for (int j = 0; j < 2; ++j)
        MFMA(acc[mi][j], a[mi], bl[j]);
    __builtin_amdgcn_s_setprio(0);
    if (lastt) { VMCNT(0); } else { VMCNT(4); }   // B1(kt) landed
    BARRIER();

    // ---- P1: read b-high (chunk B1) ; MFMA high
#pragma unroll
    for (int j = 0; j < 2; ++j)
      bh[j] = *(const bf16x8*)(S + 8192 + (128 + j * 64 + wnq + fr) * 32 + tt);
    __builtin_amdgcn_s_setprio(1);
#pragma unroll
    for (int mi = 0; mi < 8; ++mi)
#pragma unroll
      for (int j = 0; j < 2; ++j)
        MFMA(acc[mi][2 + j], a[mi], bh[j]);
    __builtin_amdgcn_s_setprio(0);
    if (!lastt) { VMCNT(1); }   // A0',A1',B0' landed for next P0; B1' in flight
    BARRIER();
  }

  const int rq = (lane >> 4) * 4, cl = lane & 15;
#pragma unroll
  for (int mi = 0; mi < 8; ++mi) {
#pragma unroll
    for (int r = 0; r < 4; ++r) {
      int grow = m0 + wm + mi * 16 + rq + r;
      bf16* orow = h2 + (size_t)grow * Cn + n0;
#pragma unroll
      for (int ni = 0; ni < 4; ++ni) {
        int col = (ni >> 1) * 128 + (ni & 1) * 64 + wnq + cl;
        orow[col] = (bf16)acc[mi][ni][r];
      }
    }
  }
}

// ---------------- combine: out[t] = h2[r0(t)] + h2[r1(t)] ---------------------
__global__ __launch_bounds__(256) void combine_kernel(
    const bf16* __restrict__ h2, const int* __restrict__ inv_rows,
    float* __restrict__ out)
{
  int t = blockIdx.x;
  int r0 = inv_rows[2 * t], r1 = inv_rows[2 * t + 1];
  int c = threadIdx.x * 4;
  bf16x4 a = *(const bf16x4*)(h2 + (size_t)r0 * Cn + c);
  bf16x4 b = *(const bf16x4*)(h2 + (size_t)r1 * Cn + c);
  float4 v;
  v.x = (float)a[0] + (float)b[0];
  v.y = (float)a[1] + (float)b[1];
  v.z = (float)a[2] + (float)b[2];
  v.w = (float)a[3] + (float)b[3];
  *(float4*)(out + (size_t)t * Cn + c) = v;
}

// ---------------- host launch ------------------------------------------------
extern "C" void kernel_launch(void* const* d_in, const int* in_sizes, int n_in,
                              void* d_out, int out_size, void* d_ws, size_t ws_size,
                              hipStream_t stream)
{
  const float* x     = (const float*)d_in[0];
  const float* wgate = (const float*)d_in[1];
  const float* wg    = (const float*)d_in[2];
  const float* wu    = (const float*)d_in[3];
  const float* wd    = (const float*)d_in[4];

  char* ws = (char*)d_ws;
  int* counts = (int*)ws;
  int* fill   = counts + 8;
  int* off    = fill + 8;
  size_t o = 256;
  int*   topk_i   = (int*)(ws + o);   o += (size_t)Tn * 2 * 4;
  float* topk_w   = (float*)(ws + o); o += (size_t)Tn * 2 * 4;
  int*   tok_list = (int*)(ws + o);   o += (size_t)MAXROWS * 4;
  float* wgt_list = (float*)(ws + o); o += (size_t)MAXROWS * 4;
  int*   inv_rows = (int*)(ws + o);   o += (size_t)Tn * 2 * 4;
  o = (o + 255) & ~(size_t)255;
  const size_t WSZ = (size_t)En * Fn * Cn;
  bf16* wgT = (bf16*)(ws + o); o += WSZ * 2;
  bf16* wuT = (bf16*)(ws + o); o += WSZ * 2;
  bf16* wdT = (bf16*)(ws + o); o += WSZ * 2;
  bf16* xg  = (bf16*)(ws + o); o += (size_t)MAXROWS * Cn * 2;
  bf16* h2  = (bf16*)(ws + o); o += (size_t)MAXROWS * Cn * 2;
  bf16* h   = (bf16*)(ws + o);

  size_t havail = ws_size > o ? ws_size - o : 0;
  long crows = (long)(havail / ((size_t)Fn * 2));
  crows &= ~(long)255;
  if (crows > MAXROWS) crows = MAXROWS;
  if (crows < 256) crows = 256;
  const int chunk_rows = (int)crows;
  const int nch = (MAXROWS + chunk_rows - 1) / chunk_rows;

  hipMemsetAsync(counts, 0, 256, stream);
  hipMemsetAsync(tok_list, 0xFF, (size_t)MAXROWS * 4, stream);

  transpose_cvt<<<dim3(Cn / 64, Fn / 64, En), 256, 0, stream>>>(wg, wgT, Cn, Fn);
  transpose_cvt<<<dim3(Cn / 64, Fn / 64, En), 256, 0, stream>>>(wu, wuT, Cn, Fn);
  transpose_cvt<<<dim3(Fn / 64, Cn / 64, En), 256, 0, stream>>>(wd, wdT, Fn, Cn);

  gate_kernel<<<Tn / 4, 256, 0, stream>>>(x, wgate, topk_i, topk_w, counts);
  offsets_kernel<<<1, 64, 0, stream>>>(counts, fill, off);
  scatter_kernel<<<Tn / 256, 256, 0, stream>>>(topk_i, topk_w, fill, tok_list, wgt_list, inv_rows);
  gather_x<<<MAXROWS, 256, 0, stream>>>(x, tok_list, xg);

  const int mt = chunk_rows / 256;
  const int gy1 = mt < 34 ? mt : 34;
  for (int c = 0; c < nch; ++c) {
    int row_lo = c * chunk_rows;
    gemm1_kernel<<<dim3((Fn + 127) / 128, gy1), 512, 0, stream>>>(
        xg, wgT, wuT, off, counts, wgt_list, h, row_lo, mt);
    gemm2_kernel<<<dim3(Cn / 256, mt), 512, 0, stream>>>(
        h, wdT, off, h2, row_lo);
  }
  combine_kernel<<<Tn, 256, 0, stream>>>(h2, inv_rows, (float*)d_out);
}

// Round 5
// 807.122 us; speedup vs baseline: 1.0220x; 1.0220x over previous
//
#include <hip/hip_runtime.h>

#define Tn      8192
#define Cn      1024
#define En      8
#define Fn      2752
#define MAXROWS 18432
#define NT1     16      // Cn/64 K-tiles for gemm1
#define NT2     43      // Fn/64 K-tiles for gemm2

typedef __bf16 bf16;
typedef bf16  bf16x8 __attribute__((ext_vector_type(8)));
typedef bf16  bf16x4 __attribute__((ext_vector_type(4)));
typedef float f32x4  __attribute__((ext_vector_type(4)));

__device__ __forceinline__ void gload16(const bf16* g, bf16* l) {
  __builtin_amdgcn_global_load_lds(
      (const __attribute__((address_space(1))) unsigned int*)g,
      (__attribute__((address_space(3))) unsigned int*)l, 16, 0, 0);
}

#define BARRIER() __builtin_amdgcn_s_barrier()
#define LGKM0()   asm volatile("s_waitcnt lgkmcnt(0)" ::: "memory")
#define VMCNT(N)  asm volatile("s_waitcnt vmcnt(" #N ")" ::: "memory")
#define MFMA(d, va, vb) d = __builtin_amdgcn_mfma_f32_16x16x32_bf16(va, vb, d, 0, 0, 0)

// bijective XCD-chunk swizzle: consecutive remapped ids land on the same XCD.
__device__ __forceinline__ int xcd_swz(int flat, int nwg) {
  int xcd = flat & 7, loc = flat >> 3;
  int q = nwg >> 3, r = nwg & 7;
  return (xcd < r ? xcd * (q + 1) : r * (q + 1) + (xcd - r) * q) + loc;
}

// ---------------- gating ------------------------------------------------------
__global__ __launch_bounds__(256) void gate_kernel(
    const float* __restrict__ x, const float* __restrict__ wgate,
    int* __restrict__ topk_i, float* __restrict__ topk_w, int* __restrict__ counts)
{
  int lane = threadIdx.x & 63;
  int wid  = threadIdx.x >> 6;
  int t = blockIdx.x * 4 + wid;
  const float* xr = x + (size_t)t * Cn;
  float acc[En];
#pragma unroll
  for (int e = 0; e < En; ++e) acc[e] = 0.f;
  for (int c = lane; c < Cn; c += 64) {
    float xv = xr[c];
#pragma unroll
    for (int e = 0; e < En; ++e) acc[e] = fmaf(xv, wgate[e * Cn + c], acc[e]);
  }
#pragma unroll
  for (int e = 0; e < En; ++e) {
#pragma unroll
    for (int o = 32; o > 0; o >>= 1) acc[e] += __shfl_xor(acc[e], o, 64);
  }
  if (lane == 0) {
    float mx = acc[0];
#pragma unroll
    for (int e = 1; e < En; ++e) mx = fmaxf(mx, acc[e]);
    float p[En], Z = 0.f;
#pragma unroll
    for (int e = 0; e < En; ++e) { p[e] = __expf(acc[e] - mx); Z += p[e]; }
    int i0 = 0;
#pragma unroll
    for (int e = 1; e < En; ++e) if (p[e] > p[i0]) i0 = e;
    int i1 = (i0 == 0) ? 1 : 0;
#pragma unroll
    for (int e = 0; e < En; ++e) if (e != i0 && p[e] > p[i1]) i1 = e;
    float s0 = p[i0] / Z, s1 = p[i1] / Z;
    float inv = 1.f / (s0 + s1 + 1e-9f);
    topk_i[2 * t] = i0;       topk_i[2 * t + 1] = i1;
    topk_w[2 * t] = s0 * inv; topk_w[2 * t + 1] = s1 * inv;
    atomicAdd(&counts[i0], 1);
    atomicAdd(&counts[i1], 1);
  }
}

__global__ void offsets_kernel(const int* __restrict__ counts,
                               int* __restrict__ fill, int* __restrict__ off)
{
  if (threadIdx.x == 0 && blockIdx.x == 0) {
    int o = 0;
    for (int e = 0; e < En; ++e) {
      off[e]  = o;
      fill[e] = o;
      o += (counts[e] + 255) & ~255;   // 256-row expert padding
    }
    off[En] = o;
  }
}

__global__ __launch_bounds__(256) void scatter_kernel(
    const int* __restrict__ topk_i, const float* __restrict__ topk_w,
    int* __restrict__ fill, int* __restrict__ tok_list, float* __restrict__ wgt_list,
    int* __restrict__ inv_rows)
{
  int t = blockIdx.x * 256 + threadIdx.x;
#pragma unroll
  for (int j = 0; j < 2; ++j) {
    int e = topk_i[2 * t + j];
    int pos = atomicAdd(&fill[e], 1);
    tok_list[pos] = t;
    wgt_list[pos] = topk_w[2 * t + j];
    inv_rows[2 * t + j] = pos;
  }
}

__global__ __launch_bounds__(256) void gather_x(
    const float* __restrict__ x, const int* __restrict__ tok_list, bf16* __restrict__ xg)
{
  int row = blockIdx.x;
  int tok = tok_list[row];
  int c = threadIdx.x * 4;
  float4 v = make_float4(0.f, 0.f, 0.f, 0.f);
  if (tok >= 0) v = *(const float4*)(x + (size_t)tok * Cn + c);
  bf16x4 pv;
  pv[0] = (bf16)v.x; pv[1] = (bf16)v.y; pv[2] = (bf16)v.z; pv[3] = (bf16)v.w;
  *(bf16x4*)(xg + (size_t)row * Cn + c) = pv;
}

// ---------------- fast transpose + fp32->bf16 ---------------------------------
__global__ __launch_bounds__(256) void transpose_cvt(
    const float* __restrict__ src, bf16* __restrict__ dst, int M, int N)
{
  __shared__ float L[64][65];
  src += (size_t)blockIdx.z * M * N;
  dst += (size_t)blockIdx.z * M * N;
  const int bm = blockIdx.x * 64;
  const int bn = blockIdx.y * 64;
  const int tid = threadIdx.x;
  const int mr = tid >> 4, nseg = tid & 15;
#pragma unroll
  for (int p = 0; p < 4; ++p) {
    int m = p * 16 + mr;
    float4 v = *(const float4*)(src + (size_t)(bm + m) * N + bn + nseg * 4);
    L[nseg * 4 + 0][m] = v.x;
    L[nseg * 4 + 1][m] = v.y;
    L[nseg * 4 + 2][m] = v.z;
    L[nseg * 4 + 3][m] = v.w;
  }
  __syncthreads();
  const int nr = tid >> 3, mseg = tid & 7;
#pragma unroll
  for (int q = 0; q < 2; ++q) {
    int n = q * 32 + nr;
    bf16x8 w;
#pragma unroll
    for (int j = 0; j < 8; ++j) w[j] = (bf16)L[n][mseg * 8 + j];
    *(bf16x8*)(dst + (size_t)(bn + n) * M + bm + mseg * 8) = w;
  }
}

// LDS ksub layout ([R][32] regions, 64B rows = 4 x 16B slots):
//   LDS[row][slot] = G[row][slot ^ ((row>>1)&3)]   -> conflict-free b128 frag reads
// staging lane: row = tid>>2, gseg = (tid&3) ^ ((tid>>3)&3)
// frag read:   slot = q ^ ((fr>>1)&3),  q = lane>>4, fr = lane&15

// ---------------- GEMM1: h = wgt * silu(xg@wgT') * (xg@wuT') ------------------
// 256m x 128F block, 512 thr / 8 waves (wave 128m x 32F x {g,u}), BK=64,
// dbuf 128KB ring. 4 phases/K-tile; every half-tile gets >=2-4 phases between
// issue and first read; counted waits only at P0/P3 ends.
// Stage stream per tile: {As0@P0, As1@P1, Bg@P2, Bu@P3}, 2 gloads each.
__global__ __launch_bounds__(512, 2) void gemm1_kernel(
    const bf16* __restrict__ xg, const bf16* __restrict__ wgT, const bf16* __restrict__ wuT,
    const int* __restrict__ off, const int* __restrict__ counts,
    const float* __restrict__ wgt_list, bf16* __restrict__ h, int row_lo)
{
  const int gdx = gridDim.x;                 // 22
  const int nwg = gdx * gridDim.y;
  const int sw = xcd_swz(blockIdx.y * gdx + blockIdx.x, nwg);
  const int bx = sw % gdx, by = sw / gdx;

  const int m0 = row_lo + by * 256;
  if (m0 >= off[En]) return;
  int e = 0;
  while (off[e + 1] <= m0) ++e;
  const int base = off[e], cnt = counts[e];
  const int n0F = bx * 128;

  // per-buffer (elems): A-s0 [256][32] @0, A-s1 @8192,
  //                     Bg-s0 [128][32] @16384, Bg-s1 @20480, Bu-s0 @24576, Bu-s1 @28672
  __shared__ bf16 sm[2][32768];              // 128 KB

  const int tid = threadIdx.x;
  const int lane = tid & 63, wid = tid >> 6;
  const int wm  = (wid >> 2) * 128;          // wave m-half
  const int wnv = (wid & 3) * 32;            // wave F-window
  const int fr = lane & 15, q = lane >> 4;
  const int lrow = tid >> 2;                 // staging row 0..127
  const int gseg = (tid & 3) ^ ((tid >> 3) & 3);
  const int tt = (q ^ ((fr >> 1) & 3)) * 8;

  int brow = n0F + lrow; if (brow > Fn - 1) brow = Fn - 1;   // ragged F tail clamp
  const bf16* a0p = xg + (size_t)(m0 + lrow) * Cn + gseg * 8;        // rows 0-127
  const bf16* a1p = a0p + (size_t)128 * Cn;                          // rows 128-255
  const bf16* bgp = wgT + (size_t)e * Fn * Cn + (size_t)brow * Cn + gseg * 8;
  const bf16* bup = wuT + (size_t)e * Fn * Cn + (size_t)brow * Cn + gseg * 8;

  f32x4 accg[2][4][2], accu[2][4][2];        // [qm][mi][nj]
#pragma unroll
  for (int qm = 0; qm < 2; ++qm)
#pragma unroll
    for (int mi = 0; mi < 4; ++mi)
#pragma unroll
      for (int nj = 0; nj < 2; ++nj) { accg[qm][mi][nj] = (f32x4)(0.f); accu[qm][mi][nj] = (f32x4)(0.f); }

  // prologue: stage tile 0 in stream order
  {
    bf16* N = &sm[0][0];
    gload16(a0p,      N + tid * 8);           // As0
    gload16(a1p,      N + 4096  + tid * 8);
    gload16(a0p + 32, N + 8192  + tid * 8);   // As1
    gload16(a1p + 32, N + 12288 + tid * 8);
    gload16(bgp,      N + 16384 + tid * 8);   // Bg
    gload16(bgp + 32, N + 20480 + tid * 8);
    gload16(bup,      N + 24576 + tid * 8);   // Bu
    gload16(bup + 32, N + 28672 + tid * 8);
  }
  VMCNT(2);            // As0,As1,Bg landed; Bu in flight
  BARRIER();

  for (int kt = 0; kt < NT1; ++kt) {
    const bf16* S = &sm[kt & 1][0];
    bf16* N = &sm[(kt + 1) & 1][0];
    const bool lastt = (kt == NT1 - 1);
    const int ko = (kt + 1) * 64;

    bf16x8 a[4][2], bg[2][2], bu[2][2];

    // ---- P0: ds a-lo(8) + bg(4) ; stage As0' ; MFMA gate m-lo (16)
#pragma unroll
    for (int mi = 0; mi < 4; ++mi)
#pragma unroll
      for (int s = 0; s < 2; ++s)
        a[mi][s] = *(const bf16x8*)(S + s * 8192 + (wm + mi * 16 + fr) * 32 + tt);
#pragma unroll
    for (int nj = 0; nj < 2; ++nj)
#pragma unroll
      for (int s = 0; s < 2; ++s)
        bg[nj][s] = *(const bf16x8*)(S + 16384 + s * 4096 + (wnv + nj * 16 + fr) * 32 + tt);
    if (!lastt) { gload16(a0p + ko, N + tid * 8); gload16(a1p + ko, N + 4096 + tid * 8); }
    BARRIER();
    LGKM0();
    __builtin_amdgcn_s_setprio(1);
#pragma unroll
    for (int s = 0; s < 2; ++s)
#pragma unroll
      for (int mi = 0; mi < 4; ++mi)
#pragma unroll
        for (int nj = 0; nj < 2; ++nj)
          MFMA(accg[0][mi][nj], a[mi][s], bg[nj][s]);
    __builtin_amdgcn_s_setprio(0);
    if (lastt) { VMCNT(0); } else { VMCNT(2); }   // Bu(kt) landed for P1
    BARRIER();

    // ---- P1: ds bu(4) ; stage As1' ; MFMA up m-lo (16)
#pragma unroll
    for (int nj = 0; nj < 2; ++nj)
#pragma unroll
      for (int s = 0; s < 2; ++s)
        bu[nj][s] = *(const bf16x8*)(S + 24576 + s * 4096 + (wnv + nj * 16 + fr) * 32 + tt);
    if (!lastt) { gload16(a0p + ko + 32, N + 8192 + tid * 8); gload16(a1p + ko + 32, N + 12288 + tid * 8); }
    BARRIER();
    LGKM0();
    __builtin_amdgcn_s_setprio(1);
#pragma unroll
    for (int s = 0; s < 2; ++s)
#pragma unroll
      for (int mi = 0; mi < 4; ++mi)
#pragma unroll
        for (int nj = 0; nj < 2; ++nj)
          MFMA(accu[0][mi][nj], a[mi][s], bu[nj][s]);
    __builtin_amdgcn_s_setprio(0);
    BARRIER();

    // ---- P2: ds a-hi(8) ; stage Bg' ; MFMA up m-hi (16)
#pragma unroll
    for (int mi = 0; mi < 4; ++mi)
#pragma unroll
      for (int s = 0; s < 2; ++s)
        a[mi][s] = *(const bf16x8*)(S + s * 8192 + (wm + 64 + mi * 16 + fr) * 32 + tt);
    if (!lastt) { gload16(bgp + ko, N + 16384 + tid * 8); gload16(bgp + ko + 32, N + 20480 + tid * 8); }
    BARRIER();
    LGKM0();
    __builtin_amdgcn_s_setprio(1);
#pragma unroll
    for (int s = 0; s < 2; ++s)
#pragma unroll
      for (int mi = 0; mi < 4; ++mi)
#pragma unroll
        for (int nj = 0; nj < 2; ++nj)
          MFMA(accu[1][mi][nj], a[mi][s], bu[nj][s]);
    __builtin_amdgcn_s_setprio(0);
    BARRIER();

    // ---- P3: stage Bu' ; MFMA gate m-hi (16, regs only)
    if (!lastt) { gload16(bup + ko, N + 24576 + tid * 8); gload16(bup + ko + 32, N + 28672 + tid * 8); }
    BARRIER();
    __builtin_amdgcn_s_setprio(1);
#pragma unroll
    for (int s = 0; s < 2; ++s)
#pragma unroll
      for (int mi = 0; mi < 4; ++mi)
#pragma unroll
        for (int nj = 0; nj < 2; ++nj)
          MFMA(accg[1][mi][nj], a[mi][s], bg[nj][s]);
    __builtin_amdgcn_s_setprio(0);
    if (!lastt) { VMCNT(2); }   // As0',As1',Bg' landed for next P0; Bu' in flight
    BARRIER();
  }

  // epilogue: h = wgt * u * silu(g)
  const int rq = (lane >> 4) * 4, cl = lane & 15;
#pragma unroll
  for (int qm = 0; qm < 2; ++qm)
#pragma unroll
    for (int mi = 0; mi < 4; ++mi)
#pragma unroll
      for (int r = 0; r < 4; ++r) {
        int grow = m0 + wm + qm * 64 + mi * 16 + rq + r;
        float w = (grow - base < cnt) ? wgt_list[grow] : 0.f;
        bf16* hr = h + (size_t)(grow - row_lo) * Fn + n0F;
#pragma unroll
        for (int nj = 0; nj < 2; ++nj) {
          int fc = wnv + nj * 16;
          if (n0F + fc < Fn) {
            float g = accg[qm][mi][nj][r], u = accu[qm][mi][nj][r];
            hr[fc + cl] = (bf16)(w * u * (g / (1.f + __expf(-g))));
          }
        }
      }
}

// ---------------- GEMM2: h2[row] = h[row] @ wdT' ------------------------------
// 128m x 256n block, 512 thr / 8 waves (wave 64m x 64n), BK=64, 96KB ring.
// 4 phases/K-tile; stream {As0@P0, As1@P1, BQlo@P2, BQhi@P3};
// waits only end-P3 vmcnt(2), end-P0 vmcnt(1). grid 4n x (rows/128) = 576 blocks.
__global__ __launch_bounds__(512, 2) void gemm2_kernel(
    const bf16* __restrict__ h, const bf16* __restrict__ wdT,
    const int* __restrict__ off, bf16* __restrict__ h2, int row_lo)
{
  const int gdy = gridDim.y;
  const int nwg = gridDim.x * gdy;
  const int sw = xcd_swz(blockIdx.x * gdy + blockIdx.y, nwg);   // n-major: B-panel L2 reuse
  const int bx = sw / gdy, by = sw % gdy;

  const int m0 = row_lo + by * 128;
  if (m0 >= off[En]) return;
  int e = 0;
  while (off[e + 1] <= m0) ++e;
  const int n0 = bx * 256;

  // per-buffer (elems): A-s0 [128][32] @0, A-s1 @4096,
  //                     B-s0 [256perm][32] @8192, B-s1 @16384   (48 KB)
  __shared__ bf16 sm[2][24576];              // 96 KB

  const int tid = threadIdx.x;
  const int lane = tid & 63, wid = tid >> 6;
  const int wm  = (wid >> 2) * 64;           // wave m-half
  const int wq  = (wid & 3);                 // wave n-quarter (64 cols)
  const int fr = lane & 15, q = lane >> 4;
  const int lrow = tid >> 2;                 // staging row 0..127
  const int gseg = (tid & 3) ^ ((tid >> 3) & 3);
  const int tt = (q ^ ((fr >> 1) & 3)) * 8;

  const bf16* ap  = h + (size_t)(m0 - row_lo + lrow) * Fn + gseg * 8;
  const int rowBlo = (lrow & 31) + (lrow >> 5) * 64;        // n-quad-lo global rows
  const bf16* bql = wdT + (size_t)e * Cn * Fn + (size_t)(n0 + rowBlo) * Fn + gseg * 8;
  const bf16* bqh = bql + (size_t)32 * Fn;

  f32x4 acc[2][2][2][2];                     // [qm][qn][mi][nj]
#pragma unroll
  for (int qm = 0; qm < 2; ++qm)
#pragma unroll
    for (int qn = 0; qn < 2; ++qn)
#pragma unroll
      for (int mi = 0; mi < 2; ++mi)
#pragma unroll
        for (int nj = 0; nj < 2; ++nj) acc[qm][qn][mi][nj] = (f32x4)(0.f);

  // prologue: stage tile 0 in stream order {As0, As1, BQlo, BQhi}
  {
    bf16* N = &sm[0][0];
    gload16(ap,       N + tid * 8);            // As0
    gload16(ap + 32,  N + 4096  + tid * 8);    // As1
    gload16(bql,      N + 8192  + tid * 8);    // BQlo s0
    gload16(bql + 32, N + 16384 + tid * 8);    // BQlo s1
    gload16(bqh,      N + 12288 + tid * 8);    // BQhi s0
    gload16(bqh + 32, N + 20480 + tid * 8);    // BQhi s1
  }
  VMCNT(2);            // As0,As1,BQlo landed; BQhi in flight
  BARRIER();

  for (int kt = 0; kt < NT2; ++kt) {
    const bf16* S = &sm[kt & 1][0];
    bf16* N = &sm[(kt + 1) & 1][0];
    const bool lastt = (kt == NT2 - 1);
    const int ko = (kt + 1) * 64;

    bf16x8 a[2][2], bl[2][2], bh[2][2];

    // ---- P0: ds a-lo(4) + b-lo(4) ; stage As0' ; MFMA (qm0,qn0) 8
#pragma unroll
    for (int mi = 0; mi < 2; ++mi)
#pragma unroll
      for (int s = 0; s < 2; ++s)
        a[mi][s] = *(const bf16x8*)(S + s * 4096 + (wm + mi * 16 + fr) * 32 + tt);
#pragma unroll
    for (int nj = 0; nj < 2; ++nj)
#pragma unroll
      for (int s = 0; s < 2; ++s)
        bl[nj][s] = *(const bf16x8*)(S + 8192 + s * 8192 + (wq * 32 + nj * 16 + fr) * 32 + tt);
    if (!lastt) { gload16(ap + ko, N + tid * 8); }
    BARRIER();
    LGKM0();
    __builtin_amdgcn_s_setprio(1);
#pragma unroll
    for (int s = 0; s < 2; ++s)
#pragma unroll
      for (int mi = 0; mi < 2; ++mi)
#pragma unroll
        for (int nj = 0; nj < 2; ++nj)
          MFMA(acc[0][0][mi][nj], a[mi][s], bl[nj][s]);
    __builtin_amdgcn_s_setprio(0);
    if (lastt) { VMCNT(0); } else { VMCNT(1); }   // BQhi(kt) landed for P1
    BARRIER();

    // ---- P1: ds b-hi(4) ; stage As1' ; MFMA (qm0,qn1) 8
#pragma unroll
    for (int nj = 0; nj < 2; ++nj)
#pragma unroll
      for (int s = 0; s < 2; ++s)
        bh[nj][s] = *(const bf16x8*)(S + 8192 + s * 8192 + (128 + wq * 32 + nj * 16 + fr) * 32 + tt);
    if (!lastt) { gload16(ap + ko + 32, N + 4096 + tid * 8); }
    BARRIER();
    LGKM0();
    __builtin_amdgcn_s_setprio(1);
#pragma unroll
    for (int s = 0; s < 2; ++s)
#pragma unroll
      for (int mi = 0; mi < 2; ++mi)
#pragma unroll
        for (int nj = 0; nj < 2; ++nj)
          MFMA(acc[0][1][mi][nj], a[mi][s], bh[nj][s]);
    __builtin_amdgcn_s_setprio(0);
    BARRIER();

    // ---- P2: ds a-hi(4) ; stage BQlo' ; MFMA (qm1,qn1) 8
#pragma unroll
    for (int mi = 0; mi < 2; ++mi)
#pragma unroll
      for (int s = 0; s < 2; ++s)
        a[mi][s] = *(const bf16x8*)(S + s * 4096 + (wm + 32 + mi * 16 + fr) * 32 + tt);
    if (!lastt) { gload16(bql + ko, N + 8192 + tid * 8); gload16(bql + ko + 32, N + 16384 + tid * 8); }
    BARRIER();
    LGKM0();
    __builtin_amdgcn_s_setprio(1);
#pragma unroll
    for (int s = 0; s < 2; ++s)
#pragma unroll
      for (int mi = 0; mi < 2; ++mi)
#pragma unroll
        for (int nj = 0; nj < 2; ++nj)
          MFMA(acc[1][1][mi][nj], a[mi][s], bh[nj][s]);
    __builtin_amdgcn_s_setprio(0);
    BARRIER();

    // ---- P3: stage BQhi' ; MFMA (qm1,qn0) 8 (regs only)
    if (!lastt) { gload16(bqh + ko, N + 12288 + tid * 8); gload16(bqh + ko + 32, N + 20480 + tid * 8); }
    BARRIER();
    __builtin_amdgcn_s_setprio(1);
#pragma unroll
    for (int s = 0; s < 2; ++s)
#pragma unroll
      for (int mi = 0; mi < 2; ++mi)
#pragma unroll
        for (int nj = 0; nj < 2; ++nj)
          MFMA(acc[1][0][mi][nj], a[mi][s], bl[nj][s]);
    __builtin_amdgcn_s_setprio(0);
    if (!lastt) { VMCNT(2); }   // As0',As1',BQlo' landed for next P0; BQhi' in flight
    BARRIER();
  }

  const int rq = (lane >> 4) * 4, cl = lane & 15;
#pragma unroll
  for (int qm = 0; qm < 2; ++qm)
#pragma unroll
    for (int mi = 0; mi < 2; ++mi)
#pragma unroll
      for (int r = 0; r < 4; ++r) {
        int grow = m0 + wm + qm * 32 + mi * 16 + rq + r;
        bf16* orow = h2 + (size_t)grow * Cn + n0 + wq * 64;
#pragma unroll
        for (int qn = 0; qn < 2; ++qn)
#pragma unroll
          for (int nj = 0; nj < 2; ++nj)
            orow[qn * 32 + nj * 16 + cl] = (bf16)acc[qm][qn][mi][nj][r];
      }
}

// ---------------- combine: out[t] = h2[r0(t)] + h2[r1(t)] ---------------------
__global__ __launch_bounds__(256) void combine_kernel(
    const bf16* __restrict__ h2, const int* __restrict__ inv_rows,
    float* __restrict__ out)
{
  int t = blockIdx.x;
  int r0 = inv_rows[2 * t], r1 = inv_rows[2 * t + 1];
  int c = threadIdx.x * 4;
  bf16x4 a = *(const bf16x4*)(h2 + (size_t)r0 * Cn + c);
  bf16x4 b = *(const bf16x4*)(h2 + (size_t)r1 * Cn + c);
  float4 v;
  v.x = (float)a[0] + (float)b[0];
  v.y = (float)a[1] + (float)b[1];
  v.z = (float)a[2] + (float)b[2];
  v.w = (float)a[3] + (float)b[3];
  *(float4*)(out + (size_t)t * Cn + c) = v;
}

// ---------------- host launch ------------------------------------------------
extern "C" void kernel_launch(void* const* d_in, const int* in_sizes, int n_in,
                              void* d_out, int out_size, void* d_ws, size_t ws_size,
                              hipStream_t stream)
{
  const float* x     = (const float*)d_in[0];
  const float* wgate = (const float*)d_in[1];
  const float* wg    = (const float*)d_in[2];
  const float* wu    = (const float*)d_in[3];
  const float* wd    = (const float*)d_in[4];

  char* ws = (char*)d_ws;
  int* counts = (int*)ws;
  int* fill   = counts + 8;
  int* off    = fill + 8;
  size_t o = 256;
  int*   topk_i   = (int*)(ws + o);   o += (size_t)Tn * 2 * 4;
  float* topk_w   = (float*)(ws + o); o += (size_t)Tn * 2 * 4;
  int*   tok_list = (int*)(ws + o);   o += (size_t)MAXROWS * 4;
  float* wgt_list = (float*)(ws + o); o += (size_t)MAXROWS * 4;
  int*   inv_rows = (int*)(ws + o);   o += (size_t)Tn * 2 * 4;
  o = (o + 255) & ~(size_t)255;
  const size_t WSZ = (size_t)En * Fn * Cn;
  bf16* wgT = (bf16*)(ws + o); o += WSZ * 2;
  bf16* wuT = (bf16*)(ws + o); o += WSZ * 2;
  bf16* wdT = (bf16*)(ws + o); o += WSZ * 2;
  bf16* xg  = (bf16*)(ws + o); o += (size_t)MAXROWS * Cn * 2;
  bf16* h2  = (bf16*)(ws + o); o += (size_t)MAXROWS * Cn * 2;
  bf16* h   = (bf16*)(ws + o);

  size_t havail = ws_size > o ? ws_size - o : 0;
  long crows = (long)(havail / ((size_t)Fn * 2));
  crows &= ~(long)255;
  if (crows > MAXROWS) crows = MAXROWS;
  if (crows < 256) crows = 256;
  const int chunk_rows = (int)crows;
  const int nch = (MAXROWS + chunk_rows - 1) / chunk_rows;

  hipMemsetAsync(counts, 0, 256, stream);
  hipMemsetAsync(tok_list, 0xFF, (size_t)MAXROWS * 4, stream);

  transpose_cvt<<<dim3(Cn / 64, Fn / 64, En), 256, 0, stream>>>(wg, wgT, Cn, Fn);
  transpose_cvt<<<dim3(Cn / 64, Fn / 64, En), 256, 0, stream>>>(wu, wuT, Cn, Fn);
  transpose_cvt<<<dim3(Fn / 64, Cn / 64, En), 256, 0, stream>>>(wd, wdT, Fn, Cn);

  gate_kernel<<<Tn / 4, 256, 0, stream>>>(x, wgate, topk_i, topk_w, counts);
  offsets_kernel<<<1, 64, 0, stream>>>(counts, fill, off);
  scatter_kernel<<<Tn / 256, 256, 0, stream>>>(topk_i, topk_w, fill, tok_list, wgt_list, inv_rows);
  gather_x<<<MAXROWS, 256, 0, stream>>>(x, tok_list, xg);

  for (int c = 0; c < nch; ++c) {
    int row_lo = c * chunk_rows;
    gemm1_kernel<<<dim3((Fn + 127) / 128, chunk_rows / 256), 512, 0, stream>>>(
        xg, wgT, wuT, off, counts, wgt_list, h, row_lo);
    gemm2_kernel<<<dim3(Cn / 256, chunk_rows / 128), 512, 0, stream>>>(
        h, wdT, off, h2, row_lo);
  }
  combine_kernel<<<Tn, 256, 0, stream>>>(h2, inv_rows, (float*)d_out);
}

// Round 6
// 744.756 us; speedup vs baseline: 1.1075x; 1.0837x over previous
//
#include <hip/hip_runtime.h>

#define Tn      8192
#define Cn      1024
#define En      8
#define Fn      2752
#define MAXROWS 18432
#define NT1     32      // Cn/32 K-tiles for gemm1
#define NT2     86      // Fn/32 K-tiles for gemm2

typedef __bf16 bf16;
typedef bf16  bf16x8 __attribute__((ext_vector_type(8)));
typedef bf16  bf16x4 __attribute__((ext_vector_type(4)));
typedef float f32x4  __attribute__((ext_vector_type(4)));

__device__ __forceinline__ void gload16(const bf16* g, bf16* l) {
  __builtin_amdgcn_global_load_lds(
      (const __attribute__((address_space(1))) unsigned int*)g,
      (__attribute__((address_space(3))) unsigned int*)l, 16, 0, 0);
}

#define BARRIER() __builtin_amdgcn_s_barrier()
#define VMCNT(N)  asm volatile("s_waitcnt vmcnt(" #N ")" ::: "memory")
#define MFMA(d, va, vb) d = __builtin_amdgcn_mfma_f32_16x16x32_bf16(va, vb, d, 0, 0, 0)

// bijective XCD-chunk swizzle: consecutive remapped ids land on the same XCD.
__device__ __forceinline__ int xcd_swz(int flat, int nwg) {
  int xcd = flat & 7, loc = flat >> 3;
  int q = nwg >> 3, r = nwg & 7;
  return (xcd < r ? xcd * (q + 1) : r * (q + 1) + (xcd - r) * q) + loc;
}

// ---------------- gating ------------------------------------------------------
__global__ __launch_bounds__(256) void gate_kernel(
    const float* __restrict__ x, const float* __restrict__ wgate,
    int* __restrict__ topk_i, float* __restrict__ topk_w, int* __restrict__ counts)
{
  int lane = threadIdx.x & 63;
  int wid  = threadIdx.x >> 6;
  int t = blockIdx.x * 4 + wid;
  const float* xr = x + (size_t)t * Cn;
  float acc[En];
#pragma unroll
  for (int e = 0; e < En; ++e) acc[e] = 0.f;
  for (int c = lane; c < Cn; c += 64) {
    float xv = xr[c];
#pragma unroll
    for (int e = 0; e < En; ++e) acc[e] = fmaf(xv, wgate[e * Cn + c], acc[e]);
  }
#pragma unroll
  for (int e = 0; e < En; ++e) {
#pragma unroll
    for (int o = 32; o > 0; o >>= 1) acc[e] += __shfl_xor(acc[e], o, 64);
  }
  if (lane == 0) {
    float mx = acc[0];
#pragma unroll
    for (int e = 1; e < En; ++e) mx = fmaxf(mx, acc[e]);
    float p[En], Z = 0.f;
#pragma unroll
    for (int e = 0; e < En; ++e) { p[e] = __expf(acc[e] - mx); Z += p[e]; }
    int i0 = 0;
#pragma unroll
    for (int e = 1; e < En; ++e) if (p[e] > p[i0]) i0 = e;
    int i1 = (i0 == 0) ? 1 : 0;
#pragma unroll
    for (int e = 0; e < En; ++e) if (e != i0 && p[e] > p[i1]) i1 = e;
    float s0 = p[i0] / Z, s1 = p[i1] / Z;
    float inv = 1.f / (s0 + s1 + 1e-9f);
    topk_i[2 * t] = i0;       topk_i[2 * t + 1] = i1;
    topk_w[2 * t] = s0 * inv; topk_w[2 * t + 1] = s1 * inv;
    atomicAdd(&counts[i0], 1);
    atomicAdd(&counts[i1], 1);
  }
}

__global__ void offsets_kernel(const int* __restrict__ counts,
                               int* __restrict__ fill, int* __restrict__ off)
{
  if (threadIdx.x == 0 && blockIdx.x == 0) {
    int o = 0;
    for (int e = 0; e < En; ++e) {
      off[e]  = o;
      fill[e] = o;
      o += (counts[e] + 255) & ~255;   // 256-row expert padding
    }
    off[En] = o;
  }
}

__global__ __launch_bounds__(256) void scatter_kernel(
    const int* __restrict__ topk_i, const float* __restrict__ topk_w,
    int* __restrict__ fill, int* __restrict__ tok_list, float* __restrict__ wgt_list,
    int* __restrict__ inv_rows)
{
  int t = blockIdx.x * 256 + threadIdx.x;
#pragma unroll
  for (int j = 0; j < 2; ++j) {
    int e = topk_i[2 * t + j];
    int pos = atomicAdd(&fill[e], 1);
    tok_list[pos] = t;
    wgt_list[pos] = topk_w[2 * t + j];
    inv_rows[2 * t + j] = pos;
  }
}

__global__ __launch_bounds__(256) void gather_x(
    const float* __restrict__ x, const int* __restrict__ tok_list, bf16* __restrict__ xg)
{
  int row = blockIdx.x;
  int tok = tok_list[row];
  int c = threadIdx.x * 4;
  float4 v = make_float4(0.f, 0.f, 0.f, 0.f);
  if (tok >= 0) v = *(const float4*)(x + (size_t)tok * Cn + c);
  bf16x4 pv;
  pv[0] = (bf16)v.x; pv[1] = (bf16)v.y; pv[2] = (bf16)v.z; pv[3] = (bf16)v.w;
  *(bf16x4*)(xg + (size_t)row * Cn + c) = pv;
}

// ---------------- fast transpose + fp32->bf16 ---------------------------------
__global__ __launch_bounds__(256) void transpose_cvt(
    const float* __restrict__ src, bf16* __restrict__ dst, int M, int N)
{
  __shared__ float L[64][65];
  src += (size_t)blockIdx.z * M * N;
  dst += (size_t)blockIdx.z * M * N;
  const int bm = blockIdx.x * 64;
  const int bn = blockIdx.y * 64;
  const int tid = threadIdx.x;
  const int mr = tid >> 4, nseg = tid & 15;
#pragma unroll
  for (int p = 0; p < 4; ++p) {
    int m = p * 16 + mr;
    float4 v = *(const float4*)(src + (size_t)(bm + m) * N + bn + nseg * 4);
    L[nseg * 4 + 0][m] = v.x;
    L[nseg * 4 + 1][m] = v.y;
    L[nseg * 4 + 2][m] = v.z;
    L[nseg * 4 + 3][m] = v.w;
  }
  __syncthreads();
  const int nr = tid >> 3, mseg = tid & 7;
#pragma unroll
  for (int q = 0; q < 2; ++q) {
    int n = q * 32 + nr;
    bf16x8 w;
#pragma unroll
    for (int j = 0; j < 8; ++j) w[j] = (bf16)L[n][mseg * 8 + j];
    *(bf16x8*)(dst + (size_t)(bn + n) * M + bm + mseg * 8) = w;
  }
}

// LDS K-tile layout (BK=32, 64B rows = 4 x 16B slots):
//   LDS[row][slot] = G[row][slot ^ ((row>>1)&3)]   -> conflict-free b128 frag reads
// staging lane: row = tid>>2, gseg = (tid&3) ^ ((tid>>3)&3)
// frag read:   slot = q ^ ((fr>>1)&3),  q = lane>>4, fr = lane&15

// ---------------- GEMM1: h = wgt * silu(xg@wgT') * (xg@wuT') ------------------
// block 256 x 64 real cols (gate+up), BK=32, 4 waves, TRIPLE-buffered 72KB LDS
// (loads issued 2 K-tiles ahead), 1 barrier/K-tile. (R3 version, 260us/33%.)
__global__ __launch_bounds__(256, 2) void gemm1_kernel(
    const bf16* __restrict__ xg, const bf16* __restrict__ wgT, const bf16* __restrict__ wuT,
    const int* __restrict__ off, const int* __restrict__ counts,
    const float* __restrict__ wgt_list, bf16* __restrict__ h, int row_lo)
{
  const int gdx = gridDim.x;
  const int nwg = gdx * gridDim.y;
  const int s = xcd_swz(blockIdx.y * gdx + blockIdx.x, nwg);
  const int bx = s % gdx, by = s / gdx;

  const int m0 = row_lo + by * 256;
  if (m0 >= off[En]) return;
  int e = 0;
  while (off[e + 1] <= m0) ++e;
  const int base = off[e], cnt = counts[e];
  const int n0 = bx * 64;

  // per-buffer layout (elements): A [256r][32] @0 ; Bg [64r][32] @8192 ; Bu @10240
  __shared__ bf16 sm[3][12288];   // 72 KB

  const int tid = threadIdx.x;
  const int lane = tid & 63, wid = tid >> 6;
  const int wm  = (wid & 1) * 128;        // wave m-half
  const int wnv = (wid >> 1) * 32;        // wave col-half (real F cols)
  const int fr = lane & 15, q = lane >> 4;
  const int lrow = tid >> 2;              // staging row 0..63
  const int gseg = (tid & 3) ^ ((tid >> 3) & 3);
  const int tt = (q ^ ((fr >> 1) & 3)) * 8;

  const bf16* wge = wgT + (size_t)e * ((size_t)Fn * Cn);
  const bf16* wue = wuT + (size_t)e * ((size_t)Fn * Cn);
  const bf16* ag0 = xg + (size_t)(m0 + lrow) * Cn + gseg * 8;
  const bf16* ag1 = ag0 + (size_t)64 * Cn;
  const bf16* ag2 = ag0 + (size_t)128 * Cn;
  const bf16* ag3 = ag0 + (size_t)192 * Cn;
  const bf16* bgp = wge + (size_t)(n0 + lrow) * Cn + gseg * 8;
  const bf16* bup = wue + (size_t)(n0 + lrow) * Cn + gseg * 8;

  f32x4 accg[8][2], accu[8][2];
#pragma unroll
  for (int mi = 0; mi < 8; ++mi)
#pragma unroll
    for (int ni = 0; ni < 2; ++ni) { accg[mi][ni] = (f32x4)(0.f); accu[mi][ni] = (f32x4)(0.f); }

#define STG1(SRC, KOFF, DST, DOFF) gload16((SRC) + (KOFF), (DST) + (DOFF) + tid * 8)
#define ISSUE1(DST, KO) do { \
    STG1(ag0, KO, DST, 0);    STG1(ag1, KO, DST, 2048); \
    STG1(ag2, KO, DST, 4096); STG1(ag3, KO, DST, 6144); \
    STG1(bgp, KO, DST, 8192); STG1(bup, KO, DST, 10240); } while (0)

  // prologue: issue tiles 0 and 1; wait tile 0 (6 of tile 1 in flight)
  ISSUE1(&sm[0][0], 0);
  ISSUE1(&sm[1][0], 32);
  VMCNT(6);
  BARRIER();

  const bf16* Sc = &sm[0][0];   // current (tile kt)
  const bf16* Sn = &sm[1][0];   // next    (tile kt+1, landing)
  bf16*       Sf = &sm[2][0];   // far     (tile kt+2, being issued)

  for (int kt = 0; kt < NT1; ++kt) {
    bf16x8 a[8], bg[2], bu[2];
#pragma unroll
    for (int mi = 0; mi < 8; ++mi)
      a[mi] = *(const bf16x8*)(Sc + (wm + mi * 16 + fr) * 32 + tt);
#pragma unroll
    for (int ni = 0; ni < 2; ++ni) {
      bg[ni] = *(const bf16x8*)(Sc + 8192 + (wnv + ni * 16 + fr) * 32 + tt);
      bu[ni] = *(const bf16x8*)(Sc + 10240 + (wnv + ni * 16 + fr) * 32 + tt);
    }
    if (kt + 2 < NT1) ISSUE1(Sf, (kt + 2) * 32);

    __builtin_amdgcn_s_setprio(1);
#pragma unroll
    for (int mi = 0; mi < 8; ++mi)
#pragma unroll
      for (int ni = 0; ni < 2; ++ni) {
        MFMA(accg[mi][ni], a[mi], bg[ni]);
        MFMA(accu[mi][ni], a[mi], bu[ni]);
      }
    __builtin_amdgcn_s_setprio(0);

    if (kt < NT1 - 2)       { VMCNT(6); BARRIER(); }
    else if (kt == NT1 - 2) { VMCNT(0); BARRIER(); }
    // rotate buffers
    const bf16* t0 = Sc; Sc = Sn; Sn = Sf; Sf = (bf16*)t0;
  }
#undef ISSUE1
#undef STG1

  // epilogue: h = wgt * u * silu(g)
  const int rq = (lane >> 4) * 4, cl = lane & 15;
#pragma unroll
  for (int mi = 0; mi < 8; ++mi) {
#pragma unroll
    for (int r = 0; r < 4; ++r) {
      int grow = m0 + wm + mi * 16 + rq + r;
      float w = (grow - base < cnt) ? wgt_list[grow] : 0.f;
      bf16* hr = h + (size_t)(grow - row_lo) * Fn + n0;
#pragma unroll
      for (int ni = 0; ni < 2; ++ni) {
        float g = accg[mi][ni][r], u = accu[mi][ni][r];
        hr[wnv + ni * 16 + cl] = (bf16)(w * u * (g / (1.f + __expf(-g))));
      }
    }
  }
}

// ---------------- GEMM2: h2[row] = h[row] @ wdT' ------------------------------
// NEW: block 128m x 128n, BK=32, 256 thr / 4 waves (wave 64 x 64), dbuf 32KB
// -> ~4 blocks/CU, grid 8n x (rows/128) = 1152 blocks (~1.06 rounds, 4-way
// cross-block TLP). m-major flat id + XCD swizzle: A(h)-panel L2-local.
__global__ __launch_bounds__(256, 4) void gemm2_kernel(
    const bf16* __restrict__ h, const bf16* __restrict__ wdT,
    const int* __restrict__ off, bf16* __restrict__ h2, int row_lo)
{
  const int nwg = 8 * gridDim.y;
  const int s = xcd_swz(blockIdx.y * 8 + blockIdx.x, nwg);   // consecutive = n-fast
  const int bn = s & 7, bm = s >> 3;

  const int m0 = row_lo + bm * 128;
  if (m0 >= off[En]) return;
  int e = 0;
  while (off[e + 1] <= m0) ++e;
  const int n0 = bn * 128;

  // per-buffer (elements): A [128r][32] @0 (4096) ; B [128r][32] @4096
  __shared__ bf16 sm[2][8192];               // 32 KB

  const int tid = threadIdx.x;
  const int lane = tid & 63, wid = tid >> 6;
  const int wrow = (wid & 1) * 64;           // wave m-half
  const int wcol = (wid >> 1) * 64;          // wave n-half
  const int fr = lane & 15, q = lane >> 4;
  const int lrow = tid >> 2;                 // staging row 0..63
  const int gseg = (tid & 3) ^ ((tid >> 3) & 3);
  const int tt = (q ^ ((fr >> 1) & 3)) * 8;

  const bf16* ap0 = h   + (size_t)(m0 - row_lo + lrow) * Fn + gseg * 8;
  const bf16* ap1 = ap0 + (size_t)64 * Fn;
  const bf16* bp0 = wdT + (size_t)e * Cn * Fn + (size_t)(n0 + lrow) * Fn + gseg * 8;
  const bf16* bp1 = bp0 + (size_t)64 * Fn;

  f32x4 acc[4][4];
#pragma unroll
  for (int mi = 0; mi < 4; ++mi)
#pragma unroll
    for (int ni = 0; ni < 4; ++ni) acc[mi][ni] = (f32x4)(0.f);

  // prologue: stage tile 0
  {
    bf16* N = &sm[0][0];
    gload16(ap0, N + tid * 8);
    gload16(ap1, N + 2048 + tid * 8);
    gload16(bp0, N + 4096 + tid * 8);
    gload16(bp1, N + 6144 + tid * 8);
  }
  VMCNT(0);
  BARRIER();

  for (int kt = 0; kt < NT2; ++kt) {
    const bf16* S = &sm[kt & 1][0];
    bf16* Nx = &sm[(kt + 1) & 1][0];
    const int ko = (kt + 1) * 32;

    // issue next tile first (overlaps ds_read + MFMA below)
    if (kt + 1 < NT2) {
      gload16(ap0 + ko, Nx + tid * 8);
      gload16(ap1 + ko, Nx + 2048 + tid * 8);
      gload16(bp0 + ko, Nx + 4096 + tid * 8);
      gload16(bp1 + ko, Nx + 6144 + tid * 8);
    }

    bf16x8 a[4], b[4];
#pragma unroll
    for (int mi = 0; mi < 4; ++mi)
      a[mi] = *(const bf16x8*)(S + (wrow + mi * 16 + fr) * 32 + tt);
#pragma unroll
    for (int ni = 0; ni < 4; ++ni)
      b[ni] = *(const bf16x8*)(S + 4096 + (wcol + ni * 16 + fr) * 32 + tt);

    __builtin_amdgcn_s_setprio(1);
#pragma unroll
    for (int mi = 0; mi < 4; ++mi)
#pragma unroll
      for (int ni = 0; ni < 4; ++ni)
        MFMA(acc[mi][ni], a[mi], b[ni]);
    __builtin_amdgcn_s_setprio(0);

    VMCNT(0);
    BARRIER();
  }

  const int rq = (lane >> 4) * 4, cl = lane & 15;
#pragma unroll
  for (int mi = 0; mi < 4; ++mi) {
#pragma unroll
    for (int r = 0; r < 4; ++r) {
      int grow = m0 + wrow + mi * 16 + rq + r;
      bf16* orow = h2 + (size_t)grow * Cn + n0;
#pragma unroll
      for (int ni = 0; ni < 4; ++ni)
        orow[wcol + ni * 16 + cl] = (bf16)acc[mi][ni][r];
    }
  }
}

// ---------------- combine: out[t] = h2[r0(t)] + h2[r1(t)] ---------------------
__global__ __launch_bounds__(256) void combine_kernel(
    const bf16* __restrict__ h2, const int* __restrict__ inv_rows,
    float* __restrict__ out)
{
  int t = blockIdx.x;
  int r0 = inv_rows[2 * t], r1 = inv_rows[2 * t + 1];
  int c = threadIdx.x * 4;
  bf16x4 a = *(const bf16x4*)(h2 + (size_t)r0 * Cn + c);
  bf16x4 b = *(const bf16x4*)(h2 + (size_t)r1 * Cn + c);
  float4 v;
  v.x = (float)a[0] + (float)b[0];
  v.y = (float)a[1] + (float)b[1];
  v.z = (float)a[2] + (float)b[2];
  v.w = (float)a[3] + (float)b[3];
  *(float4*)(out + (size_t)t * Cn + c) = v;
}

// ---------------- host launch ------------------------------------------------
extern "C" void kernel_launch(void* const* d_in, const int* in_sizes, int n_in,
                              void* d_out, int out_size, void* d_ws, size_t ws_size,
                              hipStream_t stream)
{
  const float* x     = (const float*)d_in[0];
  const float* wgate = (const float*)d_in[1];
  const float* wg    = (const float*)d_in[2];
  const float* wu    = (const float*)d_in[3];
  const float* wd    = (const float*)d_in[4];

  char* ws = (char*)d_ws;
  int* counts = (int*)ws;
  int* fill   = counts + 8;
  int* off    = fill + 8;
  size_t o = 256;
  int*   topk_i   = (int*)(ws + o);   o += (size_t)Tn * 2 * 4;
  float* topk_w   = (float*)(ws + o); o += (size_t)Tn * 2 * 4;
  int*   tok_list = (int*)(ws + o);   o += (size_t)MAXROWS * 4;
  float* wgt_list = (float*)(ws + o); o += (size_t)MAXROWS * 4;
  int*   inv_rows = (int*)(ws + o);   o += (size_t)Tn * 2 * 4;
  o = (o + 255) & ~(size_t)255;
  const size_t WSZ = (size_t)En * Fn * Cn;
  bf16* wgT = (bf16*)(ws + o); o += WSZ * 2;
  bf16* wuT = (bf16*)(ws + o); o += WSZ * 2;
  bf16* wdT = (bf16*)(ws + o); o += WSZ * 2;
  bf16* xg  = (bf16*)(ws + o); o += (size_t)MAXROWS * Cn * 2;
  bf16* h2  = (bf16*)(ws + o); o += (size_t)MAXROWS * Cn * 2;
  bf16* h   = (bf16*)(ws + o);

  size_t havail = ws_size > o ? ws_size - o : 0;
  long crows = (long)(havail / ((size_t)Fn * 2));
  crows &= ~(long)255;
  if (crows > MAXROWS) crows = MAXROWS;
  if (crows < 256) crows = 256;
  const int chunk_rows = (int)crows;
  const int nch = (MAXROWS + chunk_rows - 1) / chunk_rows;

  hipMemsetAsync(counts, 0, 256, stream);
  hipMemsetAsync(tok_list, 0xFF, (size_t)MAXROWS * 4, stream);

  transpose_cvt<<<dim3(Cn / 64, Fn / 64, En), 256, 0, stream>>>(wg, wgT, Cn, Fn);
  transpose_cvt<<<dim3(Cn / 64, Fn / 64, En), 256, 0, stream>>>(wu, wuT, Cn, Fn);
  transpose_cvt<<<dim3(Fn / 64, Cn / 64, En), 256, 0, stream>>>(wd, wdT, Fn, Cn);

  gate_kernel<<<Tn / 4, 256, 0, stream>>>(x, wgate, topk_i, topk_w, counts);
  offsets_kernel<<<1, 64, 0, stream>>>(counts, fill, off);
  scatter_kernel<<<Tn / 256, 256, 0, stream>>>(topk_i, topk_w, fill, tok_list, wgt_list, inv_rows);
  gather_x<<<MAXROWS, 256, 0, stream>>>(x, tok_list, xg);

  for (int c = 0; c < nch; ++c) {
    int row_lo = c * chunk_rows;
    gemm1_kernel<<<dim3(Fn / 64, chunk_rows / 256), 256, 0, stream>>>(
        xg, wgT, wuT, off, counts, wgt_list, h, row_lo);
    gemm2_kernel<<<dim3(8, chunk_rows / 128), 256, 0, stream>>>(
        h, wdT, off, h2, row_lo);
  }
  combine_kernel<<<Tn, 256, 0, stream>>>(h2, inv_rows, (float*)d_out);
}